// Round 12
// baseline (498.129 us; speedup 1.0000x reference)
//
#include <hip/hip_runtime.h>

// GCN 2-layer on MI355X. R11: R8's proven-low-FETCH launch shape (edge-
// parallel, block=(bucket,slice), plain NB*NSLICE grid, slice=blockIdx%NSLICE
// -> XCD-locked 3.2MB L2-resident h slice; R8 measured FETCH 42MB) combined
// with SEGMENTED-REDUCTION accumulation instead of R8's per-edge LDS atomics:
// colp is dst-sorted per bucket (bucket_fill), each thread owns ~16
// consecutive sorted edges, accumulates its current dst in 16 f32 REGISTERS,
// flushes to LDS acc[256][16] only on dst boundary (~0.06 atomics/edge,
// 250x less LDS-atomic work than R8). Balanced by construction.

#define NN 100000
#define EE 1600000
#define NB 391              // buckets of 256 nodes
#define BCAP 4608           // colp slots per bucket (mean 4092, +8 sigma)
#define EPB 8192            // edges per partition block
#define PBLK ((EE + EPB - 1) / EPB)  // 196

typedef _Float16 f16;
typedef _Float16 f16x8 __attribute__((ext_vector_type(8)));
typedef float f32x4 __attribute__((ext_vector_type(4)));

__device__ __forceinline__ int load_idx(const void* p, long long i, int is64) {
    if (is64) return (int)((const long long*)p)[i];
    return ((const int*)p)[i];
}

// ---------- bucket cursor init ----------
__global__ void init_buckets(int* cursor) {
    int i = blockIdx.x * 256 + threadIdx.x;
    if (i < NB) cursor[i] = i * BCAP;
}

// ---------- partition: edges -> bucket-major packed payloads (fixed-cap) ----------
__global__ __launch_bounds__(256) void partition_kernel(const void* ei,
                                                        int* __restrict__ cursor,
                                                        unsigned* __restrict__ col32) {
    __shared__ int lh[NB], lbase[NB], lfill[NB];
    __shared__ int s_is64;
    for (int i = threadIdx.x; i < NB; i += 256) { lh[i] = 0; lfill[i] = 0; }
    if (threadIdx.x == 0) {
        const unsigned* w = (const unsigned*)ei;
        unsigned acc = 0;
        #pragma unroll
        for (int k = 0; k < 8; k++) acc |= w[2 * (k * 997 + 1) + 1];
        s_is64 = (acc == 0);
    }
    __syncthreads();
    int is64 = s_is64;
    long long base = (long long)blockIdx.x * EPB;
    #pragma unroll 4
    for (int k = 0; k < EPB / 256; k++) {
        long long i = base + k * 256 + threadIdx.x;
        if (i < EE) {
            int d = load_idx(ei, (long long)EE + i, is64);
            atomicAdd(&lh[d >> 8], 1);
        }
    }
    __syncthreads();
    for (int i = threadIdx.x; i < NB; i += 256)
        lbase[i] = lh[i] ? atomicAdd(&cursor[i], lh[i]) : 0;
    __syncthreads();
    #pragma unroll 4
    for (int k = 0; k < EPB / 256; k++) {
        long long i = base + k * 256 + threadIdx.x;
        if (i < EE) {
            int s = load_idx(ei, i, is64);
            int d = load_idx(ei, (long long)EE + i, is64);
            int b = d >> 8;
            int r = atomicAdd(&lfill[b], 1);
            col32[lbase[b] + r] = ((unsigned)s << 8) | (unsigned)(d & 255);
        }
    }
}

// ---------- per-bucket fill: dst-sort packed payloads in place; emit dinv ----------
__global__ __launch_bounds__(256) void bucket_fill_kernel(const unsigned* __restrict__ col32,
                                                          const int* __restrict__ cursor,
                                                          float* __restrict__ dinv,
                                                          unsigned* __restrict__ colp) {
    __shared__ int cnt[256], incl[256], lfill[256];
    int t = threadIdx.x, b = blockIdx.x;
    cnt[t] = 0; lfill[t] = 0;
    __syncthreads();
    int base = b * BCAP, end = cursor[b];
    for (int i = base + t; i < end; i += 256)
        atomicAdd(&cnt[col32[i] & 255u], 1);
    __syncthreads();
    incl[t] = cnt[t];
    __syncthreads();
    #pragma unroll
    for (int off = 1; off < 256; off <<= 1) {
        int v = (t >= off) ? incl[t - off] : 0;
        __syncthreads();
        if (t >= off) incl[t] += v;
        __syncthreads();
    }
    int node = b * 256 + t;
    if (node < NN) dinv[node] = rsqrtf((float)(cnt[t] + 1));  // +1 = self loop
    __syncthreads();
    for (int i = base + t; i < end; i += 256) {
        unsigned p = col32[i];
        int d = p & 255u;
        int r = atomicAdd(&lfill[d], 1);
        colp[base + incl[d] - cnt[d] + r] = p;  // dst-sorted packed (src<<8|ld)
    }
}

// ---------- weight prep: split fp32 W into f16 hi/lo, transposed, XOR-swizzled ----------
__global__ void prep_split(const float* __restrict__ W1, const float* __restrict__ W2,
                           f16* __restrict__ W1h, f16* __restrict__ W1l,
                           f16* __restrict__ W2h, f16* __restrict__ W2l) {
    int t = blockIdx.x * 256 + threadIdx.x;
    if (t < 128 * 128) {
        int k = t >> 7, n = t & 127;
        float v = W1[t];
        f16 h = (f16)v;
        f16 l = (f16)(v - (float)h);
        int idx = n * 128 + (k ^ ((n & 7) << 3));
        W1h[idx] = h; W1l[idx] = l;
    } else if (t < 128 * 128 + 128 * 64) {
        int u = t - 128 * 128;
        int k = u >> 6, n = u & 63;
        float v = W2[u];
        f16 h = (f16)v;
        f16 l = (f16)(v - (float)h);
        int idx = n * 128 + (k ^ ((n & 7) << 3));
        W2h[idx] = h; W2l[idx] = l;
    }
}

// ---------- GEMM via f16 MFMA, hi/lo split; slice-major H out, prescaled ----------
template <int M, int SPLIT_A>
__global__ __launch_bounds__(256) void gemm_mfma(const void* __restrict__ Xv,
                                                 const f16* __restrict__ Wh,
                                                 const f16* __restrict__ Wl,
                                                 const float* __restrict__ dinv,
                                                 f16* __restrict__ H) {
    __shared__ f16 wsh[M * 128];
    __shared__ f16 wsl[M * 128];
    const int tid = threadIdx.x;
    for (int c = tid; c < M * 16; c += 256) {
        *(float4*)&wsh[c * 8] = ((const float4*)Wh)[c];
        *(float4*)&wsl[c * 8] = ((const float4*)Wl)[c];
    }
    __syncthreads();

    const int lane = tid & 63;
    const int wv = tid >> 6;
    const int m0 = lane & 15;
    const int kg = lane >> 4;
    int row = blockIdx.x * 64 + wv * 16 + m0;
    if (row >= NN) row = NN - 1;  // clamp; stores are guarded

    constexpr int NT = M / 16;
    f32x4 acc[NT];
    #pragma unroll
    for (int i = 0; i < NT; i++) acc[i] = (f32x4){0.f, 0.f, 0.f, 0.f};

    #pragma unroll
    for (int kt = 0; kt < 4; ++kt) {
        int k0 = kt * 32 + kg * 8;
        f16x8 ah, al;
        if (SPLIT_A) {
            const float* xr = (const float*)Xv + (size_t)row * 128 + k0;
            float xv[8];
            *(float4*)&xv[0] = *(const float4*)xr;
            *(float4*)&xv[4] = *(const float4*)(xr + 4);
            #pragma unroll
            for (int r = 0; r < 8; r++) {
                ah[r] = (f16)xv[r];
                al[r] = (f16)(xv[r] - (float)ah[r]);
            }
        } else {
            const f16* xp = (const f16*)Xv;
            ah = *(const f16x8*)(xp + ((size_t)(k0 >> 4) * NN + row) * 16 + (k0 & 15));
        }
        #pragma unroll
        for (int nt = 0; nt < NT; ++nt) {
            int n = nt * 16 + m0;
            int sch = (kt * 4 + kg) ^ (n & 7);
            int off = n * 128 + sch * 8;
            f16x8 bh = *(const f16x8*)&wsh[off];
            f16x8 bl = *(const f16x8*)&wsl[off];
            acc[nt] = __builtin_amdgcn_mfma_f32_16x16x32_f16(ah, bh, acc[nt], 0, 0, 0);
            if (SPLIT_A)
                acc[nt] = __builtin_amdgcn_mfma_f32_16x16x32_f16(al, bh, acc[nt], 0, 0, 0);
            acc[nt] = __builtin_amdgcn_mfma_f32_16x16x32_f16(ah, bl, acc[nt], 0, 0, 0);
        }
    }

    // C/D layout (m89-verified): col = lane&15, row = (lane>>4)*4 + reg
    int r0 = blockIdx.x * 64 + wv * 16 + kg * 4;
    float dv[4];
    #pragma unroll
    for (int i = 0; i < 4; i++) {
        int r = r0 + i;
        dv[i] = (r < NN) ? dinv[r] : 0.f;
    }
    #pragma unroll
    for (int nt = 0; nt < NT; ++nt) {
        #pragma unroll
        for (int i = 0; i < 4; i++) {
            int r = r0 + i;
            if (r < NN) H[((size_t)nt * NN + r) * 16 + m0] = (f16)(acc[nt][i] * dv[i]);
        }
    }
}

// ---------- aggregation: edge-parallel segmented reduction ----------
// Block = (bucket b, slice s). Thread owns ~E_b/256 consecutive dst-sorted
// edges; accumulates current dst in 16 f32 regs; flushes to LDS on boundary.
template <int NSLICE, bool RELU, bool OUT16>
__global__ __launch_bounds__(256) void agg_edge(const f16* __restrict__ hs,
                                                const unsigned* __restrict__ colp,
                                                const int* __restrict__ cursor,
                                                const float* __restrict__ dinv,
                                                const float* __restrict__ bias,
                                                void* __restrict__ outv) {
    __shared__ float lacc[256][16];
    int t = threadIdx.x;
    int b = blockIdx.x / NSLICE;
    int s = blockIdx.x % NSLICE;  // XCD = blockIdx%8 -> one slice per XCD
    #pragma unroll
    for (int k = 0; k < 16; k++) lacc[t][k] = 0.f;
    __syncthreads();
    int base = b * BCAP, end = cursor[b];
    int nE = end - base;
    int K = (nE + 255) >> 8;           // edges per thread
    int j0 = base + t * K;
    int j1 = min(j0 + K, end);
    const f16x8* hp = (const f16x8*)(hs + (size_t)s * NN * 16);
    float a[16];
    #pragma unroll
    for (int k = 0; k < 16; k++) a[k] = 0.f;
    int cur = -1;
    for (int j = j0; j < j1; ++j) {
        unsigned p = __builtin_nontemporal_load(&colp[j]);
        int ld = (int)(p & 255u);
        int src = (int)(p >> 8);
        if (ld != cur) {
            if (cur >= 0) {
                #pragma unroll
                for (int k = 0; k < 16; k++) atomicAdd(&lacc[cur][k], a[k]);
                #pragma unroll
                for (int k = 0; k < 16; k++) a[k] = 0.f;
            }
            cur = ld;
        }
        f16x8 v0 = hp[(unsigned)(src * 2)];
        f16x8 v1 = hp[(unsigned)(src * 2 + 1)];
        #pragma unroll
        for (int k = 0; k < 8; k++) { a[k] += (float)v0[k]; a[k + 8] += (float)v1[k]; }
    }
    if (cur >= 0) {
        #pragma unroll
        for (int k = 0; k < 16; k++) atomicAdd(&lacc[cur][k], a[k]);
    }
    __syncthreads();
    int node = b * 256 + t;
    if (node >= NN) return;
    float di = dinv[node];
    f16x8 s0 = hp[(unsigned)(node * 2)];
    f16x8 s1 = hp[(unsigned)(node * 2 + 1)];
    const float* bp = bias + s * 16;
    float o[16];
    #pragma unroll
    for (int k = 0; k < 8; k++) {
        o[k] = fmaf(lacc[t][k] + (float)s0[k], di, bp[k]);
        o[k + 8] = fmaf(lacc[t][k + 8] + (float)s1[k], di, bp[k + 8]);
    }
    if (RELU) {
        #pragma unroll
        for (int k = 0; k < 16; k++) o[k] = fmaxf(o[k], 0.f);
    }
    if (OUT16) {
        f16x8 w0, w1;
        #pragma unroll
        for (int k = 0; k < 8; k++) { w0[k] = (f16)o[k]; w1[k] = (f16)o[k + 8]; }
        f16x8* op = (f16x8*)outv;
        op[((size_t)s * NN + node) * 2] = w0;
        op[((size_t)s * NN + node) * 2 + 1] = w1;
    } else {
        float* op = (float*)outv + (size_t)node * (NSLICE * 16) + s * 16;
        #pragma unroll
        for (int k = 0; k < 4; k++) {
            f32x4 v = {o[k * 4], o[k * 4 + 1], o[k * 4 + 2], o[k * 4 + 3]};
            __builtin_nontemporal_store(v, (f32x4*)(op + k * 4));
        }
    }
}

extern "C" void kernel_launch(void* const* d_in, const int* in_sizes, int n_in,
                              void* d_out, int out_size, void* d_ws, size_t ws_size,
                              hipStream_t stream) {
    const float* x  = (const float*)d_in[0];
    const void*  ei = d_in[1];
    const float* W1 = (const float*)d_in[2];
    const float* b1 = (const float*)d_in[3];
    const float* W2 = (const float*)d_in[4];
    const float* b2 = (const float*)d_in[5];
    float* out = (float*)d_out;

    char* wsp = (char*)d_ws;
    size_t off = 0;
    auto alloc = [&](size_t bytes) {
        void* p = wsp + off;
        off += (bytes + 255) & ~(size_t)255;
        return p;
    };
    f16*      h1     = (f16*)alloc((size_t)NN * 128 * 2);  // slice-major [8][NN][16]
    f16*      a1     = (f16*)alloc((size_t)NN * 128 * 2);  // slice-major [8][NN][16]
    f16*      h2     = (f16*)alloc((size_t)NN * 64 * 2);   // slice-major [4][NN][16]
    unsigned* col32  = (unsigned*)alloc((size_t)NB * BCAP * 4);  // 7.2MB (unsorted)
    unsigned* colp   = (unsigned*)alloc((size_t)NB * BCAP * 4);  // 7.2MB (dst-sorted)
    float*    dinv   = (float*)alloc((size_t)NN * 4);
    int*      cursor = (int*)alloc((size_t)NB * 4);
    f16*      W1h    = (f16*)alloc(128 * 128 * 2);
    f16*      W1l    = (f16*)alloc(128 * 128 * 2);
    f16*      W2h    = (f16*)alloc(64 * 128 * 2);
    f16*      W2l    = (f16*)alloc(64 * 128 * 2);
    (void)ws_size; (void)in_sizes; (void)n_in; (void)out_size;

    prep_split<<<96, 256, 0, stream>>>(W1, W2, W1h, W1l, W2h, W2l);
    init_buckets<<<2, 256, 0, stream>>>(cursor);
    partition_kernel<<<PBLK, 256, 0, stream>>>(ei, cursor, col32);
    bucket_fill_kernel<<<NB, 256, 0, stream>>>(col32, cursor, dinv, colp);

    gemm_mfma<128, 1><<<(NN + 63) / 64, 256, 0, stream>>>(x, W1h, W1l, dinv, h1);
    agg_edge<8, true, true><<<NB * 8, 256, 0, stream>>>(h1, colp, cursor, dinv, b1, a1);
    gemm_mfma<64, 0><<<(NN + 63) / 64, 256, 0, stream>>>(a1, W2h, W2l, dinv, h2);
    agg_edge<4, false, false><<<NB * 4, 256, 0, stream>>>(h2, colp, cursor, dinv, b2, out);
}

// Round 13
// 216.496 us; speedup vs baseline: 2.3009x; 2.3009x over previous
//
#include <hip/hip_runtime.h>

// GCN 2-layer on MI355X. R12 = revert to the R6 structure (197us, best) +
// the two R7 deltas that were individually verified good, WITHOUT the
// degree-sort machinery that caused R7's net regression:
//  - gemm epilogue prescales h rows by dinv (agg drops per-edge dinv loads)
//  - wide-fragment agg: 16 lanes x 16B = one fully-coalesced 256B row per
//    gather instruction, 4 edges per instruction (R7: agg128 64.6us, FETCH
//    195.6MB = the 8-XCD x h-matrix traffic floor), node = wid directly.
// R8-R12 slice/XCD-affinity arc abandoned: 1-in-5 reproducibility, net loss.

#define NN 100000
#define EE 1600000
#define NB 391              // buckets of 256 nodes
#define BCAP 4608           // raw col32 slots per bucket (mean 4092, +8 sigma)
#define PCAP 6656           // padded col slots per bucket
#define EPB 8192            // edges per partition block
#define PBLK ((EE + EPB - 1) / EPB)  // 196

typedef _Float16 f16;
typedef _Float16 f16x8 __attribute__((ext_vector_type(8)));
typedef _Float16 f16x4 __attribute__((ext_vector_type(4)));
typedef float f32x4 __attribute__((ext_vector_type(4)));

__device__ __forceinline__ int load_idx(const void* p, long long i, int is64) {
    if (is64) return (int)((const long long*)p)[i];
    return ((const int*)p)[i];
}

// ---------- bucket cursor init ----------
__global__ void init_buckets(int* cursor) {
    int i = blockIdx.x * 256 + threadIdx.x;
    if (i < NB) cursor[i] = i * BCAP;
}

// ---------- partition: edges -> bucket-major packed payloads (fixed-cap) ----------
__global__ __launch_bounds__(256) void partition_kernel(const void* ei,
                                                        int* __restrict__ cursor,
                                                        unsigned* __restrict__ col32) {
    __shared__ int lh[NB], lbase[NB], lfill[NB];
    __shared__ int s_is64;
    for (int i = threadIdx.x; i < NB; i += 256) { lh[i] = 0; lfill[i] = 0; }
    if (threadIdx.x == 0) {
        const unsigned* w = (const unsigned*)ei;
        unsigned acc = 0;
        #pragma unroll
        for (int k = 0; k < 8; k++) acc |= w[2 * (k * 997 + 1) + 1];
        s_is64 = (acc == 0);
    }
    __syncthreads();
    int is64 = s_is64;
    long long base = (long long)blockIdx.x * EPB;
    #pragma unroll 4
    for (int k = 0; k < EPB / 256; k++) {
        long long i = base + k * 256 + threadIdx.x;
        if (i < EE) {
            int d = load_idx(ei, (long long)EE + i, is64);
            atomicAdd(&lh[d >> 8], 1);
        }
    }
    __syncthreads();
    for (int i = threadIdx.x; i < NB; i += 256)
        lbase[i] = lh[i] ? atomicAdd(&cursor[i], lh[i]) : 0;
    __syncthreads();
    #pragma unroll 4
    for (int k = 0; k < EPB / 256; k++) {
        long long i = base + k * 256 + threadIdx.x;
        if (i < EE) {
            int s = load_idx(ei, i, is64);
            int d = load_idx(ei, (long long)EE + i, is64);
            int b = d >> 8;
            int r = atomicAdd(&lfill[b], 1);
            col32[lbase[b] + r] = ((unsigned)s << 8) | (unsigned)(d & 255);
        }
    }
}

// ---------- per-bucket fill: emits rsp/dinv/padded col ----------
__global__ __launch_bounds__(256) void bucket_fill_kernel(const unsigned* __restrict__ col32,
                                                          const int* __restrict__ cursor,
                                                          int2* __restrict__ rsp,
                                                          float* __restrict__ dinv,
                                                          int* __restrict__ col) {
    __shared__ int cnt[256], incl[256], lfill[256];
    int t = threadIdx.x, b = blockIdx.x;
    cnt[t] = 0; lfill[t] = 0;
    __syncthreads();
    int base = b * BCAP;
    int end = cursor[b];
    for (int i = base + t; i < end; i += 256)
        atomicAdd(&cnt[col32[i] & 255u], 1);
    __syncthreads();
    int pc = (cnt[t] + 7) & ~7;  // padded degree (multiple of 8)
    incl[t] = pc;
    __syncthreads();
    #pragma unroll
    for (int off = 1; off < 256; off <<= 1) {
        int v = (t >= off) ? incl[t - off] : 0;
        __syncthreads();
        if (t >= off) incl[t] += v;
        __syncthreads();
    }
    int node = b * 256 + t;
    int excl = (t == 0) ? 0 : incl[t - 1];
    int myrs = b * PCAP + excl;
    if (node < NN) {
        rsp[node] = make_int2(myrs, pc);
        dinv[node] = rsqrtf((float)(cnt[t] + 1));  // +1 = self loop
    }
    __syncthreads();
    for (int i = base + t; i < end; i += 256) {
        unsigned p = col32[i];
        int d = p & 255u;
        int r = atomicAdd(&lfill[d], 1);
        int ex = (d == 0) ? 0 : incl[d - 1];
        col[b * PCAP + ex + r] = (int)(p >> 8);
    }
    __syncthreads();
    int cn = cnt[t];
    for (int k = cn; k < pc; k++) col[myrs + k] = NN;  // pad slots -> sentinel
    if (t == 255) {  // tail pad: unconditional first-batch col reads
        int tot = incl[255];
        for (int k = 0; k < 8; k++) col[b * PCAP + tot + k] = NN;
    }
}

// ---------- weight prep: split fp32 W into f16 hi/lo, transposed, XOR-swizzled ----------
__global__ void prep_split(const float* __restrict__ W1, const float* __restrict__ W2,
                           f16* __restrict__ W1h, f16* __restrict__ W1l,
                           f16* __restrict__ W2h, f16* __restrict__ W2l) {
    int t = blockIdx.x * 256 + threadIdx.x;
    if (t < 128 * 128) {
        int k = t >> 7, n = t & 127;
        float v = W1[t];
        f16 h = (f16)v;
        f16 l = (f16)(v - (float)h);
        int idx = n * 128 + (k ^ ((n & 7) << 3));
        W1h[idx] = h; W1l[idx] = l;
    } else if (t < 128 * 128 + 128 * 64) {
        int u = t - 128 * 128;
        int k = u >> 6, n = u & 63;
        float v = W2[u];
        f16 h = (f16)v;
        f16 l = (f16)(v - (float)h);
        int idx = n * 128 + (k ^ ((n & 7) << 3));
        W2h[idx] = h; W2l[idx] = l;
    }
}

// ---------- GEMM via f16 MFMA, hi/lo split; row-major H, prescaled by dinv ----------
template <int M, int SPLIT_A>
__global__ __launch_bounds__(256) void gemm_mfma(const void* __restrict__ Xv,
                                                 const f16* __restrict__ Wh,
                                                 const f16* __restrict__ Wl,
                                                 const float* __restrict__ dinv,
                                                 f16* __restrict__ H) {
    __shared__ f16 wsh[M * 128];
    __shared__ f16 wsl[M * 128];
    const int tid = threadIdx.x;
    for (int c = tid; c < M * 16; c += 256) {
        *(float4*)&wsh[c * 8] = ((const float4*)Wh)[c];
        *(float4*)&wsl[c * 8] = ((const float4*)Wl)[c];
    }
    __syncthreads();

    const int lane = tid & 63;
    const int wv = tid >> 6;
    const int m0 = lane & 15;
    const int kg = lane >> 4;
    int row = blockIdx.x * 64 + wv * 16 + m0;
    if (row >= NN) row = NN - 1;  // clamp; stores are guarded

    constexpr int NT = M / 16;
    f32x4 acc[NT];
    #pragma unroll
    for (int i = 0; i < NT; i++) acc[i] = (f32x4){0.f, 0.f, 0.f, 0.f};

    #pragma unroll
    for (int kt = 0; kt < 4; ++kt) {
        int k0 = kt * 32 + kg * 8;
        f16x8 ah, al;
        if (SPLIT_A) {
            const float* xr = (const float*)Xv + (size_t)row * 128 + k0;
            float xv[8];
            *(float4*)&xv[0] = *(const float4*)xr;
            *(float4*)&xv[4] = *(const float4*)(xr + 4);
            #pragma unroll
            for (int r = 0; r < 8; r++) {
                ah[r] = (f16)xv[r];
                al[r] = (f16)(xv[r] - (float)ah[r]);
            }
        } else {
            ah = *(const f16x8*)((const f16*)Xv + (size_t)row * 128 + k0);
        }
        #pragma unroll
        for (int nt = 0; nt < NT; ++nt) {
            int n = nt * 16 + m0;
            int sch = (kt * 4 + kg) ^ (n & 7);
            int off = n * 128 + sch * 8;
            f16x8 bh = *(const f16x8*)&wsh[off];
            f16x8 bl = *(const f16x8*)&wsl[off];
            acc[nt] = __builtin_amdgcn_mfma_f32_16x16x32_f16(ah, bh, acc[nt], 0, 0, 0);
            if (SPLIT_A)
                acc[nt] = __builtin_amdgcn_mfma_f32_16x16x32_f16(al, bh, acc[nt], 0, 0, 0);
            acc[nt] = __builtin_amdgcn_mfma_f32_16x16x32_f16(ah, bl, acc[nt], 0, 0, 0);
        }
    }

    // C/D layout (m89-verified): col = lane&15, row = (lane>>4)*4 + reg
    int r0 = blockIdx.x * 64 + wv * 16 + kg * 4;
    float dv[4];
    #pragma unroll
    for (int i = 0; i < 4; i++) {
        int r = r0 + i;
        dv[i] = (r < NN) ? dinv[r] : 0.f;
    }
    #pragma unroll
    for (int nt = 0; nt < NT; ++nt) {
        int cidx = nt * 16 + m0;
        #pragma unroll
        for (int i = 0; i < 4; i++) {
            int r = r0 + i;
            if (r < NN) H[(size_t)r * M + cidx] = (f16)(acc[nt][i] * dv[i]);
        }
    }
}

// ---------- agg D=128: 16 lanes x f16x8 per row (256B coalesced), 8 edges/iter ----------
__global__ __launch_bounds__(256) void agg128(const f16* __restrict__ h,
                                              const int2* __restrict__ rsp,
                                              const int* __restrict__ col,
                                              const float* __restrict__ dinv,
                                              const float* __restrict__ bias,
                                              f16* __restrict__ out) {
    int node = (blockIdx.x * 256 + threadIdx.x) >> 6;
    if (node >= NN) return;
    int lane = threadIdx.x & 63;
    int grp = lane >> 4, gl = lane & 15;
    int2 g = rsp[node];
    int s = g.x, e = g.x + g.y;  // multiple of 8; col tail-padded
    const f16x8* hp = (const f16x8*)h;  // row = 16 f16x8
    float acc[8];
    #pragma unroll
    for (int k = 0; k < 8; k++) acc[k] = 0.f;
    int c0 = col[s + grp], c1 = col[s + 4 + grp];
    for (int j = s; j < e; j += 8) {
        int n0 = col[j + 8 + grp];
        int n1 = col[j + 12 + grp];
        f16x8 v0 = hp[(unsigned)(c0 * 16 + gl)];
        f16x8 v1 = hp[(unsigned)(c1 * 16 + gl)];
        #pragma unroll
        for (int k = 0; k < 8; k++) acc[k] += (float)v0[k];
        #pragma unroll
        for (int k = 0; k < 8; k++) acc[k] += (float)v1[k];
        c0 = n0; c1 = n1;
    }
    #pragma unroll
    for (int k = 0; k < 8; k++) acc[k] += __shfl_xor(acc[k], 32);
    #pragma unroll
    for (int k = 0; k < 8; k++) acc[k] += __shfl_xor(acc[k], 16);
    if (grp == 0) {
        f16x8 sv = hp[(unsigned)(node * 16 + gl)];  // self (prescaled)
        float di = dinv[node];
        float4 b0 = ((const float4*)bias)[gl * 2];
        float4 b1 = ((const float4*)bias)[gl * 2 + 1];
        float bb[8] = {b0.x, b0.y, b0.z, b0.w, b1.x, b1.y, b1.z, b1.w};
        f16x8 o;
        #pragma unroll
        for (int k = 0; k < 8; k++) {
            float v = fmaf(acc[k] + (float)sv[k], di, bb[k]);
            o[k] = (f16)fmaxf(v, 0.f);
        }
        ((f16x8*)out)[(unsigned)(node * 16 + gl)] = o;
    }
}

// ---------- agg D=64: 16 lanes x f16x4 per row (128B coalesced), 8 edges/iter ----------
__global__ __launch_bounds__(256) void agg64(const f16* __restrict__ h,
                                             const int2* __restrict__ rsp,
                                             const int* __restrict__ col,
                                             const float* __restrict__ dinv,
                                             const float* __restrict__ bias,
                                             float* __restrict__ out) {
    int node = (blockIdx.x * 256 + threadIdx.x) >> 6;
    if (node >= NN) return;
    int lane = threadIdx.x & 63;
    int grp = lane >> 4, gl = lane & 15;
    int2 g = rsp[node];
    int s = g.x, e = g.x + g.y;
    const f16x4* hp = (const f16x4*)h;  // row = 16 f16x4
    float acc[4];
    #pragma unroll
    for (int k = 0; k < 4; k++) acc[k] = 0.f;
    int c0 = col[s + grp], c1 = col[s + 4 + grp];
    for (int j = s; j < e; j += 8) {
        int n0 = col[j + 8 + grp];
        int n1 = col[j + 12 + grp];
        f16x4 v0 = hp[(unsigned)(c0 * 16 + gl)];
        f16x4 v1 = hp[(unsigned)(c1 * 16 + gl)];
        #pragma unroll
        for (int k = 0; k < 4; k++) acc[k] += (float)v0[k];
        #pragma unroll
        for (int k = 0; k < 4; k++) acc[k] += (float)v1[k];
        c0 = n0; c1 = n1;
    }
    #pragma unroll
    for (int k = 0; k < 4; k++) acc[k] += __shfl_xor(acc[k], 32);
    #pragma unroll
    for (int k = 0; k < 4; k++) acc[k] += __shfl_xor(acc[k], 16);
    if (grp == 0) {
        f16x4 sv = hp[(unsigned)(node * 16 + gl)];
        float di = dinv[node];
        float4 b = ((const float4*)bias)[gl];
        float4 o;
        o.x = fmaf(acc[0] + (float)sv[0], di, b.x);
        o.y = fmaf(acc[1] + (float)sv[1], di, b.y);
        o.z = fmaf(acc[2] + (float)sv[2], di, b.z);
        o.w = fmaf(acc[3] + (float)sv[3], di, b.w);
        ((float4*)out)[(unsigned)(node * 16 + gl)] = o;
    }
}

extern "C" void kernel_launch(void* const* d_in, const int* in_sizes, int n_in,
                              void* d_out, int out_size, void* d_ws, size_t ws_size,
                              hipStream_t stream) {
    const float* x  = (const float*)d_in[0];
    const void*  ei = d_in[1];
    const float* W1 = (const float*)d_in[2];
    const float* b1 = (const float*)d_in[3];
    const float* W2 = (const float*)d_in[4];
    const float* b2 = (const float*)d_in[5];
    float* out = (float*)d_out;

    char* wsp = (char*)d_ws;
    size_t off = 0;
    auto alloc = [&](size_t bytes) {
        void* p = wsp + off;
        off += (bytes + 255) & ~(size_t)255;
        return p;
    };
    f16*      h1     = (f16*)alloc((size_t)(NN + 1) * 128 * 2);  // +1 sentinel row
    f16*      a1     = (f16*)alloc((size_t)NN * 128 * 2);        // aliased as col32
    f16*      h2     = (f16*)alloc((size_t)(NN + 1) * 64 * 2);   // +1 sentinel row
    int*      col    = (int*)alloc((size_t)NB * PCAP * 4);       // padded CSR
    int2*     rsp    = (int2*)alloc((size_t)NN * 8);             // (start, padded_deg)
    float*    dinv   = (float*)alloc((size_t)NN * 4);
    int*      cursor = (int*)alloc((size_t)NB * 4);
    f16*      W1h    = (f16*)alloc(128 * 128 * 2);
    f16*      W1l    = (f16*)alloc(128 * 128 * 2);
    f16*      W2h    = (f16*)alloc(64 * 128 * 2);
    f16*      W2l    = (f16*)alloc(64 * 128 * 2);
    unsigned* col32  = (unsigned*)a1;  // alias: consumed before a1 is written
    (void)ws_size; (void)in_sizes; (void)n_in; (void)out_size;

    // zero sentinel rows (gathered by pad entries; must be zero)
    hipMemsetAsync(h1 + (size_t)NN * 128, 0, 256, stream);
    hipMemsetAsync(h2 + (size_t)NN * 64, 0, 128, stream);

    prep_split<<<96, 256, 0, stream>>>(W1, W2, W1h, W1l, W2h, W2l);
    init_buckets<<<2, 256, 0, stream>>>(cursor);
    partition_kernel<<<PBLK, 256, 0, stream>>>(ei, cursor, col32);
    bucket_fill_kernel<<<NB, 256, 0, stream>>>(col32, cursor, rsp, dinv, col);

    gemm_mfma<128, 1><<<(NN + 63) / 64, 256, 0, stream>>>(x, W1h, W1l, dinv, h1);
    agg128<<<(NN * 64) / 256, 256, 0, stream>>>(h1, rsp, col, dinv, b1, a1);
    gemm_mfma<64, 0><<<(NN + 63) / 64, 256, 0, stream>>>(a1, W2h, W2l, dinv, h2);
    agg64<<<(NN * 64) / 256, 256, 0, stream>>>(h2, rsp, col, dinv, b2, out);
}

// Round 14
// 199.501 us; speedup vs baseline: 2.4969x; 1.0852x over previous
//
#include <hip/hip_runtime.h>

// GCN 2-layer on MI355X. R14 = best-of-each composition:
//  - agg128: R12 wide-fragment (16 lanes x 16B = 256B/row, 4 rows/gather-inst)
//    deepened to 4 gather instructions in flight (16-edge unroll, col
//    tail-padded by 16 so prefetch needs no guards). FETCH 190MB = 8-XCD
//    structural floor; chasing the remaining ~14% latency slack.
//  - agg64: revert to R5's proven 2-nodes/wave 8-deep-MLP scalar form
//    (f16x2/lane), minus per-edge dinv (h2 prescaled in gemm epilogue).
//    R13's wide-fragment agg64 halved MLP -> +25us; reverted.
//  - CSR build, GEMMs (f16 MFMA hi/lo split, prescale): unchanged from R12.

#define NN 100000
#define EE 1600000
#define NB 391              // buckets of 256 nodes
#define BCAP 4608           // raw col32 slots per bucket (mean 4092, +8 sigma)
#define PCAP 6656           // padded col slots per bucket
#define EPB 8192            // edges per partition block
#define PBLK ((EE + EPB - 1) / EPB)  // 196

typedef _Float16 f16;
typedef _Float16 f16x8 __attribute__((ext_vector_type(8)));
typedef _Float16 f16x2 __attribute__((ext_vector_type(2)));
typedef float f32x4 __attribute__((ext_vector_type(4)));

__device__ __forceinline__ int load_idx(const void* p, long long i, int is64) {
    if (is64) return (int)((const long long*)p)[i];
    return ((const int*)p)[i];
}

// ---------- bucket cursor init ----------
__global__ void init_buckets(int* cursor) {
    int i = blockIdx.x * 256 + threadIdx.x;
    if (i < NB) cursor[i] = i * BCAP;
}

// ---------- partition: edges -> bucket-major packed payloads (fixed-cap) ----------
__global__ __launch_bounds__(256) void partition_kernel(const void* ei,
                                                        int* __restrict__ cursor,
                                                        unsigned* __restrict__ col32) {
    __shared__ int lh[NB], lbase[NB], lfill[NB];
    __shared__ int s_is64;
    for (int i = threadIdx.x; i < NB; i += 256) { lh[i] = 0; lfill[i] = 0; }
    if (threadIdx.x == 0) {
        const unsigned* w = (const unsigned*)ei;
        unsigned acc = 0;
        #pragma unroll
        for (int k = 0; k < 8; k++) acc |= w[2 * (k * 997 + 1) + 1];
        s_is64 = (acc == 0);
    }
    __syncthreads();
    int is64 = s_is64;
    long long base = (long long)blockIdx.x * EPB;
    #pragma unroll 4
    for (int k = 0; k < EPB / 256; k++) {
        long long i = base + k * 256 + threadIdx.x;
        if (i < EE) {
            int d = load_idx(ei, (long long)EE + i, is64);
            atomicAdd(&lh[d >> 8], 1);
        }
    }
    __syncthreads();
    for (int i = threadIdx.x; i < NB; i += 256)
        lbase[i] = lh[i] ? atomicAdd(&cursor[i], lh[i]) : 0;
    __syncthreads();
    #pragma unroll 4
    for (int k = 0; k < EPB / 256; k++) {
        long long i = base + k * 256 + threadIdx.x;
        if (i < EE) {
            int s = load_idx(ei, i, is64);
            int d = load_idx(ei, (long long)EE + i, is64);
            int b = d >> 8;
            int r = atomicAdd(&lfill[b], 1);
            col32[lbase[b] + r] = ((unsigned)s << 8) | (unsigned)(d & 255);
        }
    }
}

// ---------- per-bucket fill: emits rsp/dinv/padded col ----------
__global__ __launch_bounds__(256) void bucket_fill_kernel(const unsigned* __restrict__ col32,
                                                          const int* __restrict__ cursor,
                                                          int2* __restrict__ rsp,
                                                          float* __restrict__ dinv,
                                                          int* __restrict__ col) {
    __shared__ int cnt[256], incl[256], lfill[256];
    int t = threadIdx.x, b = blockIdx.x;
    cnt[t] = 0; lfill[t] = 0;
    __syncthreads();
    int base = b * BCAP;
    int end = cursor[b];
    for (int i = base + t; i < end; i += 256)
        atomicAdd(&cnt[col32[i] & 255u], 1);
    __syncthreads();
    int pc = (cnt[t] + 7) & ~7;  // padded degree (multiple of 8)
    incl[t] = pc;
    __syncthreads();
    #pragma unroll
    for (int off = 1; off < 256; off <<= 1) {
        int v = (t >= off) ? incl[t - off] : 0;
        __syncthreads();
        if (t >= off) incl[t] += v;
        __syncthreads();
    }
    int node = b * 256 + t;
    int excl = (t == 0) ? 0 : incl[t - 1];
    int myrs = b * PCAP + excl;
    if (node < NN) {
        rsp[node] = make_int2(myrs, pc);
        dinv[node] = rsqrtf((float)(cnt[t] + 1));  // +1 = self loop
    }
    __syncthreads();
    for (int i = base + t; i < end; i += 256) {
        unsigned p = col32[i];
        int d = p & 255u;
        int r = atomicAdd(&lfill[d], 1);
        int ex = (d == 0) ? 0 : incl[d - 1];
        col[b * PCAP + ex + r] = (int)(p >> 8);
    }
    __syncthreads();
    int cn = cnt[t];
    for (int k = cn; k < pc; k++) col[myrs + k] = NN;  // pad slots -> sentinel
    if (t == 255) {  // tail pad x16: 4-deep col prefetch reads up to e+15
        int tot = incl[255];
        for (int k = 0; k < 16; k++) col[b * PCAP + tot + k] = NN;
    }
}

// ---------- weight prep: split fp32 W into f16 hi/lo, transposed, XOR-swizzled ----------
__global__ void prep_split(const float* __restrict__ W1, const float* __restrict__ W2,
                           f16* __restrict__ W1h, f16* __restrict__ W1l,
                           f16* __restrict__ W2h, f16* __restrict__ W2l) {
    int t = blockIdx.x * 256 + threadIdx.x;
    if (t < 128 * 128) {
        int k = t >> 7, n = t & 127;
        float v = W1[t];
        f16 h = (f16)v;
        f16 l = (f16)(v - (float)h);
        int idx = n * 128 + (k ^ ((n & 7) << 3));
        W1h[idx] = h; W1l[idx] = l;
    } else if (t < 128 * 128 + 128 * 64) {
        int u = t - 128 * 128;
        int k = u >> 6, n = u & 63;
        float v = W2[u];
        f16 h = (f16)v;
        f16 l = (f16)(v - (float)h);
        int idx = n * 128 + (k ^ ((n & 7) << 3));
        W2h[idx] = h; W2l[idx] = l;
    }
}

// ---------- GEMM via f16 MFMA, hi/lo split; row-major H, prescaled by dinv ----------
template <int M, int SPLIT_A>
__global__ __launch_bounds__(256) void gemm_mfma(const void* __restrict__ Xv,
                                                 const f16* __restrict__ Wh,
                                                 const f16* __restrict__ Wl,
                                                 const float* __restrict__ dinv,
                                                 f16* __restrict__ H) {
    __shared__ f16 wsh[M * 128];
    __shared__ f16 wsl[M * 128];
    const int tid = threadIdx.x;
    for (int c = tid; c < M * 16; c += 256) {
        *(float4*)&wsh[c * 8] = ((const float4*)Wh)[c];
        *(float4*)&wsl[c * 8] = ((const float4*)Wl)[c];
    }
    __syncthreads();

    const int lane = tid & 63;
    const int wv = tid >> 6;
    const int m0 = lane & 15;
    const int kg = lane >> 4;
    int row = blockIdx.x * 64 + wv * 16 + m0;
    if (row >= NN) row = NN - 1;  // clamp; stores are guarded

    constexpr int NT = M / 16;
    f32x4 acc[NT];
    #pragma unroll
    for (int i = 0; i < NT; i++) acc[i] = (f32x4){0.f, 0.f, 0.f, 0.f};

    #pragma unroll
    for (int kt = 0; kt < 4; ++kt) {
        int k0 = kt * 32 + kg * 8;
        f16x8 ah, al;
        if (SPLIT_A) {
            const float* xr = (const float*)Xv + (size_t)row * 128 + k0;
            float xv[8];
            *(float4*)&xv[0] = *(const float4*)xr;
            *(float4*)&xv[4] = *(const float4*)(xr + 4);
            #pragma unroll
            for (int r = 0; r < 8; r++) {
                ah[r] = (f16)xv[r];
                al[r] = (f16)(xv[r] - (float)ah[r]);
            }
        } else {
            ah = *(const f16x8*)((const f16*)Xv + (size_t)row * 128 + k0);
        }
        #pragma unroll
        for (int nt = 0; nt < NT; ++nt) {
            int n = nt * 16 + m0;
            int sch = (kt * 4 + kg) ^ (n & 7);
            int off = n * 128 + sch * 8;
            f16x8 bh = *(const f16x8*)&wsh[off];
            f16x8 bl = *(const f16x8*)&wsl[off];
            acc[nt] = __builtin_amdgcn_mfma_f32_16x16x32_f16(ah, bh, acc[nt], 0, 0, 0);
            if (SPLIT_A)
                acc[nt] = __builtin_amdgcn_mfma_f32_16x16x32_f16(al, bh, acc[nt], 0, 0, 0);
            acc[nt] = __builtin_amdgcn_mfma_f32_16x16x32_f16(ah, bl, acc[nt], 0, 0, 0);
        }
    }

    // C/D layout (m89-verified): col = lane&15, row = (lane>>4)*4 + reg
    int r0 = blockIdx.x * 64 + wv * 16 + kg * 4;
    float dv[4];
    #pragma unroll
    for (int i = 0; i < 4; i++) {
        int r = r0 + i;
        dv[i] = (r < NN) ? dinv[r] : 0.f;
    }
    #pragma unroll
    for (int nt = 0; nt < NT; ++nt) {
        int cidx = nt * 16 + m0;
        #pragma unroll
        for (int i = 0; i < 4; i++) {
            int r = r0 + i;
            if (r < NN) H[(size_t)r * M + cidx] = (f16)(acc[nt][i] * dv[i]);
        }
    }
}

// ---------- agg D=128: 16 lanes x 16B rows, 4 gather-insts in flight ----------
__global__ __launch_bounds__(256) void agg128(const f16* __restrict__ h,
                                              const int2* __restrict__ rsp,
                                              const int* __restrict__ col,
                                              const float* __restrict__ dinv,
                                              const float* __restrict__ bias,
                                              f16* __restrict__ out) {
    int node = (blockIdx.x * 256 + threadIdx.x) >> 6;
    if (node >= NN) return;
    int lane = threadIdx.x & 63;
    int grp = lane >> 4, gl = lane & 15;
    int2 g = rsp[node];
    int s = g.x, e = g.x + g.y;  // multiple of 8; col tail-padded by 16
    const f16x8* hp = (const f16x8*)h;  // row = 16 f16x8
    float accA[8], accB[8];
    #pragma unroll
    for (int k = 0; k < 8; k++) { accA[k] = 0.f; accB[k] = 0.f; }
    // preload cols for two 8-edge batches (unguarded: tail-pad covers)
    int c0a = col[s + grp], c1a = col[s + 4 + grp];
    int c0b = col[s + 8 + grp], c1b = col[s + 12 + grp];
    int j = s;
    for (; j + 16 <= e; j += 16) {
        f16x8 v0 = hp[(unsigned)(c0a * 16 + gl)];
        f16x8 v1 = hp[(unsigned)(c1a * 16 + gl)];
        f16x8 v2 = hp[(unsigned)(c0b * 16 + gl)];
        f16x8 v3 = hp[(unsigned)(c1b * 16 + gl)];
        c0a = col[j + 16 + grp]; c1a = col[j + 20 + grp];
        c0b = col[j + 24 + grp]; c1b = col[j + 28 + grp];
        #pragma unroll
        for (int k = 0; k < 8; k++) {
            accA[k] += (float)v0[k] + (float)v1[k];
            accB[k] += (float)v2[k] + (float)v3[k];
        }
    }
    if (j < e) {  // one 8-edge batch remains (cols already in c0a/c1a)
        f16x8 v0 = hp[(unsigned)(c0a * 16 + gl)];
        f16x8 v1 = hp[(unsigned)(c1a * 16 + gl)];
        #pragma unroll
        for (int k = 0; k < 8; k++) accA[k] += (float)v0[k] + (float)v1[k];
    }
    float acc[8];
    #pragma unroll
    for (int k = 0; k < 8; k++) acc[k] = accA[k] + accB[k];
    #pragma unroll
    for (int k = 0; k < 8; k++) acc[k] += __shfl_xor(acc[k], 32);
    #pragma unroll
    for (int k = 0; k < 8; k++) acc[k] += __shfl_xor(acc[k], 16);
    if (grp == 0) {
        f16x8 sv = hp[(unsigned)(node * 16 + gl)];  // self (prescaled)
        float di = dinv[node];
        float4 b0 = ((const float4*)bias)[gl * 2];
        float4 b1 = ((const float4*)bias)[gl * 2 + 1];
        float bb[8] = {b0.x, b0.y, b0.z, b0.w, b1.x, b1.y, b1.z, b1.w};
        f16x8 o;
        #pragma unroll
        for (int k = 0; k < 8; k++) {
            float v = fmaf(acc[k] + (float)sv[k], di, bb[k]);
            o[k] = (f16)fmaxf(v, 0.f);
        }
        ((f16x8*)out)[(unsigned)(node * 16 + gl)] = o;
    }
}

// ---------- agg D=64: R5-style 32 lanes/node, f16x2/lane, 8-deep MLP ----------
__global__ __launch_bounds__(256) void agg64(const f16* __restrict__ h,
                                             const int2* __restrict__ rsp,
                                             const int* __restrict__ col,
                                             const float* __restrict__ dinv,
                                             const float* __restrict__ bias,
                                             float* __restrict__ out) {
    int node = (blockIdx.x * 256 + threadIdx.x) >> 5;
    int lane = threadIdx.x & 31;
    if (node >= NN) return;
    float di = dinv[node];
    const f16x2* hp = (const f16x2*)h;
    f16x2 sv = hp[(unsigned)(node * 32 + lane)];  // self (prescaled)
    int2 g = rsp[node];
    int s = g.x, e = g.x + g.y;  // multiple of 8
    float ax[8], ay[8];
    #pragma unroll
    for (int i = 0; i < 8; i++) { ax[i] = 0.f; ay[i] = 0.f; }
    int c[8];
    if (s < e) {
        #pragma unroll
        for (int i = 0; i < 8; i++) c[i] = col[s + i];
    }
    for (int j = s; j < e; j += 8) {
        int cn[8];
        #pragma unroll
        for (int i = 0; i < 8; i++) cn[i] = col[j + 8 + i];  // tail-pad covers
        f16x2 v[8];
        #pragma unroll
        for (int i = 0; i < 8; i++) v[i] = hp[(unsigned)(c[i] * 32 + lane)];
        #pragma unroll
        for (int i = 0; i < 8; i++) {
            ax[i] += (float)v[i][0];
            ay[i] += (float)v[i][1];
        }
        #pragma unroll
        for (int i = 0; i < 8; i++) c[i] = cn[i];
    }
    float sx = ((ax[0] + ax[1]) + (ax[2] + ax[3])) + ((ax[4] + ax[5]) + (ax[6] + ax[7]));
    float sy = ((ay[0] + ay[1]) + (ay[2] + ay[3])) + ((ay[4] + ay[5]) + (ay[6] + ay[7]));
    sx += (float)sv[0];
    sy += (float)sv[1];
    float2 bv = ((const float2*)bias)[lane];
    float2 o = make_float2(fmaf(sx, di, bv.x), fmaf(sy, di, bv.y));
    ((float2*)(out + (size_t)node * 64))[lane] = o;
}

extern "C" void kernel_launch(void* const* d_in, const int* in_sizes, int n_in,
                              void* d_out, int out_size, void* d_ws, size_t ws_size,
                              hipStream_t stream) {
    const float* x  = (const float*)d_in[0];
    const void*  ei = d_in[1];
    const float* W1 = (const float*)d_in[2];
    const float* b1 = (const float*)d_in[3];
    const float* W2 = (const float*)d_in[4];
    const float* b2 = (const float*)d_in[5];
    float* out = (float*)d_out;

    char* wsp = (char*)d_ws;
    size_t off = 0;
    auto alloc = [&](size_t bytes) {
        void* p = wsp + off;
        off += (bytes + 255) & ~(size_t)255;
        return p;
    };
    f16*      h1     = (f16*)alloc((size_t)(NN + 1) * 128 * 2);  // +1 sentinel row
    f16*      a1     = (f16*)alloc((size_t)NN * 128 * 2);        // aliased as col32
    f16*      h2     = (f16*)alloc((size_t)(NN + 1) * 64 * 2);   // +1 sentinel row
    int*      col    = (int*)alloc((size_t)(NB * PCAP + 64) * 4);  // padded CSR
    int2*     rsp    = (int2*)alloc((size_t)NN * 8);             // (start, padded_deg)
    float*    dinv   = (float*)alloc((size_t)NN * 4);
    int*      cursor = (int*)alloc((size_t)NB * 4);
    f16*      W1h    = (f16*)alloc(128 * 128 * 2);
    f16*      W1l    = (f16*)alloc(128 * 128 * 2);
    f16*      W2h    = (f16*)alloc(64 * 128 * 2);
    f16*      W2l    = (f16*)alloc(64 * 128 * 2);
    unsigned* col32  = (unsigned*)a1;  // alias: consumed before a1 is written
    (void)ws_size; (void)in_sizes; (void)n_in; (void)out_size;

    // zero sentinel rows (gathered by pad entries; must be zero)
    hipMemsetAsync(h1 + (size_t)NN * 128, 0, 256, stream);
    hipMemsetAsync(h2 + (size_t)NN * 64, 0, 128, stream);

    prep_split<<<96, 256, 0, stream>>>(W1, W2, W1h, W1l, W2h, W2l);
    init_buckets<<<2, 256, 0, stream>>>(cursor);
    partition_kernel<<<PBLK, 256, 0, stream>>>(ei, cursor, col32);
    bucket_fill_kernel<<<NB, 256, 0, stream>>>(col32, cursor, rsp, dinv, col);

    gemm_mfma<128, 1><<<(NN + 63) / 64, 256, 0, stream>>>(x, W1h, W1l, dinv, h1);
    agg128<<<(NN * 64) / 256, 256, 0, stream>>>(h1, rsp, col, dinv, b1, a1);
    gemm_mfma<64, 0><<<(NN + 63) / 64, 256, 0, stream>>>(a1, W2h, W2l, dinv, h2);
    agg64<<<(NN * 32 + 255) / 256, 256, 0, stream>>>(h2, rsp, col, dinv, b2, out);
}